// Round 1
// baseline (409.715 us; speedup 1.0000x reference)
//
#include <hip/hip_runtime.h>
#include <cstdint>
#include <cstddef>

// Problem constants
#define NN   4096   // N
#define FIN  512    // F_IN
#define FOUT 256    // F_OUT
// C = 4, channel-last -> 4 consecutive floats per element
//
// Algebra: x3 is constant along C -> FFT(x3) lives at freq 0 only, so
// h = x @ Wsum (channel-independent); then out = (sum_c adjs) @ h + bias.
// Two real GEMMs, no FFT.
//
// R2 change: k_gemm_big was latency-serialized (1 block/CU + __syncthreads'
// vmcnt(0) drain killing the A-prefetch every chunk -> HBM idle windows).
// Now: raw s_barrier + lgkmcnt(0) (loads stay in flight across barriers),
// 2-deep register A-prefetch, 32-row tiles with grid 512 = 2 blocks/CU
// (4 waves/SIMD). kq = bid&3 vs XCD round-robin (%8) keeps each XCD's
// 512 KiB B-slice L2-resident as before.

typedef short bf16x8 __attribute__((ext_vector_type(8)));
typedef float f32x4  __attribute__((ext_vector_type(4)));
typedef float f32x2  __attribute__((ext_vector_type(2)));

// Raw barrier: no vmcnt drain (global prefetch loads survive), but DS ops
// (this wave's ds_read/ds_write) must complete for cross-wave safety.
#define BAR() do { asm volatile("s_waitcnt lgkmcnt(0)" ::: "memory"); \
                   __builtin_amdgcn_s_barrier();                      \
                   asm volatile("" ::: "memory"); } while (0)

__device__ __forceinline__ unsigned short f2bf(float f) {
    union { float f; unsigned u; } v; v.f = f;
    unsigned r = v.u + 0x7FFFu + ((v.u >> 16) & 1u);   // RNE
    return (unsigned short)(r >> 16);
}
__device__ __forceinline__ unsigned pack2(float a, float b) {
    return (unsigned)f2bf(a) | ((unsigned)f2bf(b) << 16);
}

// ---------------------------------------------------------------------------
// Kernel 0: Wsum_T[r][j] = sum_c weight[j][r][c]   (bf16, [256][512] K-major)
// ---------------------------------------------------------------------------
__global__ __launch_bounds__(256) void k_prep_wsum(const f32x4* __restrict__ w4,
                                                   unsigned short* __restrict__ wsumT) {
    int t = blockIdx.x * 256 + threadIdx.x;
    int r = t & (FOUT - 1);
    int j = t >> 8;
    f32x4 v = w4[j * FOUT + r];
    wsumT[r * FIN + j] = f2bf((v.x + v.y) + (v.z + v.w));
}

// ---------------------------------------------------------------------------
// Kernel 1: H^T = (x @ Wsum)^T, bf16 [256][4096]. 16 rows x 256 cols/block,
// BK=64, 8 chunks. Raw barriers so pf/bp prefetch stays in flight.
// ---------------------------------------------------------------------------
__global__ __launch_bounds__(512) void k_gemm_h(const float* __restrict__ x,
                                                const unsigned short* __restrict__ Bt,
                                                unsigned short* __restrict__ Ht) {
    __shared__ unsigned short Abf[16 * 72];
    const int tid  = threadIdx.x;
    const int lane = tid & 63;
    const int wave = tid >> 6;
    const int quad = lane >> 4;
    const int l15  = lane & 15;
    const int i0   = blockIdx.x * 16;
    const int si   = tid >> 5;
    const int sk   = (tid & 31) * 2;

    f32x4 acc0 = {0.f, 0.f, 0.f, 0.f};
    f32x4 acc1 = {0.f, 0.f, 0.f, 0.f};

    f32x2 pf;
    bf16x8 bp00, bp01, bp10, bp11;

    auto loadA = [&](int c) {
        pf = *(const f32x2*)(x + (size_t)(i0 + si) * FIN + c * 64 + sk);
    };
    auto loadB = [&](int c, bf16x8& b00, bf16x8& b01, bf16x8& b10, bf16x8& b11) {
        const unsigned short* p0 = Bt + (size_t)(wave * 32 + l15) * FIN + c * 64 + quad * 8;
        b00 = *(const bf16x8*)(p0);
        b01 = *(const bf16x8*)(p0 + 32);
        const unsigned short* p1 = p0 + (size_t)16 * FIN;
        b10 = *(const bf16x8*)(p1);
        b11 = *(const bf16x8*)(p1 + 32);
    };

    loadA(0);
    loadB(0, bp00, bp01, bp10, bp11);

    for (int c = 0; c < FIN / 64; ++c) {
        BAR();                                   // prev reads done; loads in flight
        *(unsigned*)&Abf[si * 72 + sk] = pack2(pf.x, pf.y);
        BAR();                                   // write visible

        bf16x8 bc00 = bp00, bc01 = bp01, bc10 = bp10, bc11 = bp11;
        if (c + 1 < FIN / 64) {
            loadA(c + 1);
            loadB(c + 1, bp00, bp01, bp10, bp11);
        }
        bf16x8 a0 = *(const bf16x8*)&Abf[l15 * 72 + quad * 8];
        bf16x8 a1 = *(const bf16x8*)&Abf[l15 * 72 + 32 + quad * 8];

        acc0 = __builtin_amdgcn_mfma_f32_16x16x32_bf16(a0, bc00, acc0, 0, 0, 0);
        acc0 = __builtin_amdgcn_mfma_f32_16x16x32_bf16(a1, bc01, acc0, 0, 0, 0);
        acc1 = __builtin_amdgcn_mfma_f32_16x16x32_bf16(a0, bc10, acc1, 0, 0, 0);
        acc1 = __builtin_amdgcn_mfma_f32_16x16x32_bf16(a1, bc11, acc1, 0, 0, 0);
    }

    // D layout: col = lane&15, row = quad*4 + reg
    const int n  = wave * 32 + l15;
    const int ib = i0 + quad * 4;
    ushort4 h;
    h.x = f2bf(acc0[0]); h.y = f2bf(acc0[1]); h.z = f2bf(acc0[2]); h.w = f2bf(acc0[3]);
    *(ushort4*)(Ht + (size_t)n * NN + ib) = h;
    h.x = f2bf(acc1[0]); h.y = f2bf(acc1[1]); h.z = f2bf(acc1[2]); h.w = f2bf(acc1[3]);
    *(ushort4*)(Ht + (size_t)(n + 16) * NN + ib) = h;
}

// ---------------------------------------------------------------------------
// Kernel 2: big GEMM partials. Block = 32 rows x 256 cols x K=1024.
// grid 512: kq = bid & 3 (K-quarter), rg = bid >> 2 (row group, 0..127).
// 2 blocks/CU, raw barriers, 2-deep A prefetch -> HBM never drains.
// P[kq][row][col] f32.
// ---------------------------------------------------------------------------
#define LD 72   // LDS row stride in shorts (144 B: 16B-aligned for b128)
__global__ __launch_bounds__(512, 4) void k_gemm_big(const f32x4* __restrict__ adjs4,
                                                     const unsigned short* __restrict__ Bt,
                                                     float* __restrict__ P) {
    __shared__ unsigned short Abf[2][32 * LD];

    const int tid  = threadIdx.x;
    const int lane = tid & 63;
    const int wave = tid >> 6;
    const int quad = lane >> 4;
    const int l15  = lane & 15;

    const int kq   = blockIdx.x & 3;
    const int rg   = blockIdx.x >> 2;
    const int row0 = rg * 32;
    const size_t kbase = (size_t)kq * 1024;

    const int sr = tid >> 4;        // staging row 0..31
    const int sc = tid & 15;        // staging col group 0..15

    f32x4 acc[2][2];
#pragma unroll
    for (int m = 0; m < 2; ++m)
#pragma unroll
        for (int n = 0; n < 2; ++n)
            acc[m][n] = (f32x4){0.f, 0.f, 0.f, 0.f};

    f32x4 pa[2][4];                 // 2-deep A prefetch: pa[k&1] holds chunk k
    bf16x8 pb[2][2];                // B prefetch: [ntile][kstep]

    auto loadA = [&](int c) {
        const f32x4* ap = adjs4 + (size_t)(row0 + sr) * NN + kbase + c * 64;
        f32x4* d = pa[c & 1];
#pragma unroll
        for (int v = 0; v < 2; ++v) {
            d[2 * v]     = __builtin_nontemporal_load(ap + sc * 2 + v * 32);
            d[2 * v + 1] = __builtin_nontemporal_load(ap + sc * 2 + v * 32 + 1);
        }
    };
    auto writeA = [&](int b, int c) {           // stage chunk c (pa[c&1]) -> buf b
        const f32x4* s = pa[c & 1];
        unsigned* dst = (unsigned*)&Abf[b][sr * LD + sc * 2];
#pragma unroll
        for (int v = 0; v < 2; ++v) {
            f32x4 p0 = s[2 * v], p1 = s[2 * v + 1];
            dst[v * 16] = pack2((p0.x + p0.y) + (p0.z + p0.w),
                                (p1.x + p1.y) + (p1.z + p1.w));
        }
    };
    auto loadB = [&](int c) {
#pragma unroll
        for (int n = 0; n < 2; ++n) {
            const unsigned short* p = Bt + (size_t)(wave * 32 + n * 16 + l15) * NN
                                        + kbase + c * 64 + quad * 8;
            pb[n][0] = *(const bf16x8*)p;
            pb[n][1] = *(const bf16x8*)(p + 32);
        }
    };

    // Prologue: stage chunk 0 into buf 0, keep chunk 1 in flight.
    loadA(0);
    loadB(0);
    writeA(0, 0);       // waits pa[0] (chunk 0)
    loadA(1);
    BAR();              // buf 0 visible; chunk-1 loads in flight

    for (int c = 0; c < 16; ++c) {
        const int b = c & 1;
        if (c + 2 < 16) loadA(c + 2);   // issue first: deepest prefetch, no waits
        bf16x8 bc[2][2] = {{pb[0][0], pb[0][1]}, {pb[1][0], pb[1][1]}};
        if (c + 1 < 16) {
            writeA(b ^ 1, c + 1);       // chunk c+1 (loaded last iter) -> other buf
            loadB(c + 1);
        }
#pragma unroll
        for (int s = 0; s < 2; ++s) {
#pragma unroll
            for (int m = 0; m < 2; ++m) {
                bf16x8 a = *(const bf16x8*)&Abf[b][(m * 16 + l15) * LD + s * 32 + quad * 8];
                acc[m][0] = __builtin_amdgcn_mfma_f32_16x16x32_bf16(a, bc[0][s], acc[m][0], 0, 0, 0);
                acc[m][1] = __builtin_amdgcn_mfma_f32_16x16x32_bf16(a, bc[1][s], acc[m][1], 0, 0, 0);
            }
        }
        BAR();          // buf b reads done + buf b^1 writes visible; VMEM survives
    }

    // epilogue: P[kq][row][col], D layout col = lane&15, row = quad*4 + reg
    float* p = P + (size_t)kq * NN * FOUT;
#pragma unroll
    for (int m = 0; m < 2; ++m) {
#pragma unroll
        for (int n = 0; n < 2; ++n) {
            const int col = wave * 32 + n * 16 + l15;
#pragma unroll
            for (int r = 0; r < 4; ++r) {
                const int row = row0 + m * 16 + quad * 4 + r;
                p[(size_t)row * FOUT + col] = acc[m][n][r];
            }
        }
    }
}

// ---------------------------------------------------------------------------
// Kernel 3: out = (P0+P1+P2+P3) + bias
// ---------------------------------------------------------------------------
__global__ __launch_bounds__(256) void k_reduce(const float* __restrict__ P,
                                                const f32x4* __restrict__ bias4,
                                                f32x4* __restrict__ out4) {
    const int idx = blockIdx.x * 256 + threadIdx.x;     // (i,col) flat, 1M total
    const size_t STR = (size_t)NN * FOUT;
    float s = (P[idx] + P[idx + STR]) + (P[idx + 2 * STR] + P[idx + 3 * STR]);
    f32x4 bv = bias4[idx];
    f32x4 o;
    o.x = s + bv.x; o.y = s + bv.y; o.z = s + bv.z; o.w = s + bv.w;
    out4[idx] = o;
}

// ---------------------------------------------------------------------------
extern "C" void kernel_launch(void* const* d_in, const int* in_sizes, int n_in,
                              void* d_out, int out_size, void* d_ws, size_t ws_size,
                              hipStream_t stream) {
    const float* x     = (const float*)d_in[0];    // [4096][512] f32
    const f32x4* adjs4 = (const f32x4*)d_in[1];    // [4096][4096] x f32x4 (C=4)
    const f32x4* w4    = (const f32x4*)d_in[2];    // [512][256] x f32x4
    const f32x4* bias4 = (const f32x4*)d_in[3];    // [4096][256] x f32x4
    f32x4*       out4  = (f32x4*)d_out;            // [4096][256] x f32x4

    char* ws = (char*)d_ws;
    unsigned short* wsumT = (unsigned short*)ws;                       // 256 KiB
    unsigned short* Ht    = (unsigned short*)(ws + 262144);            // 2 MiB
    float*          Pp    = (float*)(ws + 262144 + 2097152);           // 16 MiB

    k_prep_wsum<<<(FIN * FOUT) / 256, 256, 0, stream>>>(w4, wsumT);
    k_gemm_h<<<NN / 16, 512, 0, stream>>>(x, wsumT, Ht);
    k_gemm_big<<<512, 512, 0, stream>>>(adjs4, Ht, Pp);
    k_reduce<<<(NN * FOUT) / 256, 256, 0, stream>>>(Pp, bias4, out4);
}

// Round 2
// 392.028 us; speedup vs baseline: 1.0451x; 1.0451x over previous
//
#include <hip/hip_runtime.h>
#include <cstdint>
#include <cstddef>

// Problem constants
#define NN   4096   // N
#define FIN  512    // F_IN
#define FOUT 256    // F_OUT
// C = 4, channel-last -> 4 consecutive floats per element
//
// Algebra: x3 is constant along C -> FFT(x3) lives at freq 0 only, so
// h = x @ Wsum (channel-independent); then out = (sum_c adjs) @ h + bias.
// Two real GEMMs, no FFT.
//
// R2 post-mortem: R1's bundle (32-row tiles, grid 512, 2-deep prefetch, raw
// barriers everywhere) regressed 395.7 -> 409.7 us. Chunk BW-time (2.6 us)
// > HBM latency (0.9 us), so R0's vmcnt(0) drain was mostly paying
// unavoidable BW time, and halving the tile doubled B-traffic. This round:
// exact R0 structure (64-row tiles, grid 256, 1-deep prefetch), ONE change:
// k_gemm_big's __syncthreads -> raw s_barrier + lgkmcnt(0), so chunk c+1's
// in-flight A-loads keep streaming through the barrier/MFMA window
// (eliminates the ~10% HBM-idle window per chunk). Single-variable A/B.

typedef short bf16x8 __attribute__((ext_vector_type(8)));
typedef float f32x4  __attribute__((ext_vector_type(4)));
typedef float f32x2  __attribute__((ext_vector_type(2)));

// Raw barrier: no vmcnt drain (global prefetch loads survive the barrier);
// lgkmcnt(0) orders this wave's LDS ops for cross-wave safety.
#define BAR() do { asm volatile("s_waitcnt lgkmcnt(0)" ::: "memory"); \
                   __builtin_amdgcn_s_barrier();                      \
                   asm volatile("" ::: "memory"); } while (0)

__device__ __forceinline__ unsigned short f2bf(float f) {
    union { float f; unsigned u; } v; v.f = f;
    unsigned r = v.u + 0x7FFFu + ((v.u >> 16) & 1u);   // RNE
    return (unsigned short)(r >> 16);
}
__device__ __forceinline__ unsigned pack2(float a, float b) {
    return (unsigned)f2bf(a) | ((unsigned)f2bf(b) << 16);
}

// ---------------------------------------------------------------------------
// Kernel 0: Wsum_T[r][j] = sum_c weight[j][r][c]   (bf16, [256][512] K-major)
// ---------------------------------------------------------------------------
__global__ __launch_bounds__(256) void k_prep_wsum(const f32x4* __restrict__ w4,
                                                   unsigned short* __restrict__ wsumT) {
    int t = blockIdx.x * 256 + threadIdx.x;
    int r = t & (FOUT - 1);
    int j = t >> 8;
    f32x4 v = w4[j * FOUT + r];
    wsumT[r * FIN + j] = f2bf((v.x + v.y) + (v.z + v.w));
}

// ---------------------------------------------------------------------------
// Kernel 1: H^T = (x @ Wsum)^T, bf16 [256][4096]. 16 rows x 256 cols/block,
// BK=64, 8 chunks. (R0-proven structure, unchanged.)
// ---------------------------------------------------------------------------
__global__ __launch_bounds__(512) void k_gemm_h(const float* __restrict__ x,
                                                const unsigned short* __restrict__ Bt,
                                                unsigned short* __restrict__ Ht) {
    __shared__ unsigned short Abf[16 * 72];
    const int tid  = threadIdx.x;
    const int lane = tid & 63;
    const int wave = tid >> 6;
    const int quad = lane >> 4;
    const int l15  = lane & 15;
    const int i0   = blockIdx.x * 16;
    const int si   = tid >> 5;
    const int sk   = (tid & 31) * 2;

    f32x4 acc0 = {0.f, 0.f, 0.f, 0.f};
    f32x4 acc1 = {0.f, 0.f, 0.f, 0.f};

    f32x2 pf;
    bf16x8 bp00, bp01, bp10, bp11;

    auto loadA = [&](int c) {
        pf = *(const f32x2*)(x + (size_t)(i0 + si) * FIN + c * 64 + sk);
    };
    auto loadB = [&](int c, bf16x8& b00, bf16x8& b01, bf16x8& b10, bf16x8& b11) {
        const unsigned short* p0 = Bt + (size_t)(wave * 32 + l15) * FIN + c * 64 + quad * 8;
        b00 = *(const bf16x8*)(p0);
        b01 = *(const bf16x8*)(p0 + 32);
        const unsigned short* p1 = p0 + (size_t)16 * FIN;
        b10 = *(const bf16x8*)(p1);
        b11 = *(const bf16x8*)(p1 + 32);
    };

    loadA(0);
    loadB(0, bp00, bp01, bp10, bp11);

    for (int c = 0; c < FIN / 64; ++c) {
        __syncthreads();
        *(unsigned*)&Abf[si * 72 + sk] = pack2(pf.x, pf.y);
        __syncthreads();

        bf16x8 bc00 = bp00, bc01 = bp01, bc10 = bp10, bc11 = bp11;
        if (c + 1 < FIN / 64) {
            loadA(c + 1);
            loadB(c + 1, bp00, bp01, bp10, bp11);
        }
        bf16x8 a0 = *(const bf16x8*)&Abf[l15 * 72 + quad * 8];
        bf16x8 a1 = *(const bf16x8*)&Abf[l15 * 72 + 32 + quad * 8];

        acc0 = __builtin_amdgcn_mfma_f32_16x16x32_bf16(a0, bc00, acc0, 0, 0, 0);
        acc0 = __builtin_amdgcn_mfma_f32_16x16x32_bf16(a1, bc01, acc0, 0, 0, 0);
        acc1 = __builtin_amdgcn_mfma_f32_16x16x32_bf16(a0, bc10, acc1, 0, 0, 0);
        acc1 = __builtin_amdgcn_mfma_f32_16x16x32_bf16(a1, bc11, acc1, 0, 0, 0);
    }

    // D layout: col = lane&15, row = quad*4 + reg
    const int n  = wave * 32 + l15;
    const int ib = i0 + quad * 4;
    ushort4 h;
    h.x = f2bf(acc0[0]); h.y = f2bf(acc0[1]); h.z = f2bf(acc0[2]); h.w = f2bf(acc0[3]);
    *(ushort4*)(Ht + (size_t)n * NN + ib) = h;
    h.x = f2bf(acc1[0]); h.y = f2bf(acc1[1]); h.z = f2bf(acc1[2]); h.w = f2bf(acc1[3]);
    *(ushort4*)(Ht + (size_t)(n + 16) * NN + ib) = h;
}

// ---------------------------------------------------------------------------
// Kernel 2: big GEMM partials. Block = 64 rows x 256 cols x K=1024.
// grid 256: kq = bid & 3 (K-quarter), rg = bid >> 2 (row group).
// BK=64, 16 chunks, LDS double-buffered A (sum_c adjs -> bf16).
// P[kq][row][col] f32. R0 structure; barriers are raw (no vmcnt drain) so
// chunk c+1's A-loads stream through the MFMA window.
// ---------------------------------------------------------------------------
#define LD 72   // LDS row stride in shorts (144 B: 16B-aligned for b128)
__global__ __launch_bounds__(512) void k_gemm_big(const f32x4* __restrict__ adjs4,
                                                  const unsigned short* __restrict__ Bt,
                                                  float* __restrict__ P) {
    __shared__ unsigned short Abf[2][64 * LD];

    const int tid  = threadIdx.x;
    const int lane = tid & 63;
    const int wave = tid >> 6;
    const int quad = lane >> 4;
    const int l15  = lane & 15;

    const int kq   = blockIdx.x & 3;
    const int rg   = blockIdx.x >> 2;
    const int row0 = rg * 64;
    const size_t kbase = (size_t)kq * 1024;

    const int sr = tid >> 3;        // staging row 0..63
    const int sc = tid & 7;         // staging col group

    f32x4 acc[4][2];
#pragma unroll
    for (int m = 0; m < 4; ++m)
#pragma unroll
        for (int n = 0; n < 2; ++n)
            acc[m][n] = (f32x4){0.f, 0.f, 0.f, 0.f};

    f32x4 pa[8];                    // A prefetch: 8 f32x4 / thread / chunk
    bf16x8 pb[2][2];                // B prefetch: [ntile][kstep]

    auto loadA = [&](int c) {
        const f32x4* ap = adjs4 + (size_t)(row0 + sr) * NN + kbase + c * 64;
#pragma unroll
        for (int u = 0; u < 4; ++u) {
            pa[2 * u]     = __builtin_nontemporal_load(ap + sc * 2 + u * 16);
            pa[2 * u + 1] = __builtin_nontemporal_load(ap + sc * 2 + u * 16 + 1);
        }
    };
    auto writeA = [&](int b) {
        unsigned* dst = (unsigned*)&Abf[b][sr * LD + sc * 2];
#pragma unroll
        for (int u = 0; u < 4; ++u) {
            f32x4 p0 = pa[2 * u], p1 = pa[2 * u + 1];
            dst[u * 8] = pack2((p0.x + p0.y) + (p0.z + p0.w),
                               (p1.x + p1.y) + (p1.z + p1.w));
        }
    };
    auto loadB = [&](int c) {
#pragma unroll
        for (int n = 0; n < 2; ++n) {
            const unsigned short* p = Bt + (size_t)(wave * 32 + n * 16 + l15) * NN
                                        + kbase + c * 64 + quad * 8;
            pb[n][0] = *(const bf16x8*)p;
            pb[n][1] = *(const bf16x8*)(p + 32);
        }
    };

    loadA(0);
    loadB(0);

    for (int c = 0; c < 16; ++c) {
        const int b = c & 1;
        writeA(b);                          // waits (counted vmcnt) for chunk c
        if (c + 1 < 16) loadA(c + 1);       // in flight through barrier + MFMA
        BAR();                              // writes visible; VMEM survives

        bf16x8 bc[2][2] = {{pb[0][0], pb[0][1]}, {pb[1][0], pb[1][1]}};
        if (c + 1 < 16) loadB(c + 1);

#pragma unroll
        for (int s = 0; s < 2; ++s) {
#pragma unroll
            for (int m = 0; m < 4; ++m) {
                bf16x8 a = *(const bf16x8*)&Abf[b][(m * 16 + l15) * LD + s * 32 + quad * 8];
                acc[m][0] = __builtin_amdgcn_mfma_f32_16x16x32_bf16(a, bc[0][s], acc[m][0], 0, 0, 0);
                acc[m][1] = __builtin_amdgcn_mfma_f32_16x16x32_bf16(a, bc[1][s], acc[m][1], 0, 0, 0);
            }
        }
        BAR();   // protect buf b before it's rewritten at c+2; VMEM survives
    }

    // epilogue: P[kq][row][col], D layout col = lane&15, row = quad*4 + reg
    float* p = P + (size_t)kq * NN * FOUT;
#pragma unroll
    for (int m = 0; m < 4; ++m) {
#pragma unroll
        for (int n = 0; n < 2; ++n) {
            const int col = wave * 32 + n * 16 + l15;
#pragma unroll
            for (int r = 0; r < 4; ++r) {
                const int row = row0 + m * 16 + quad * 4 + r;
                p[(size_t)row * FOUT + col] = acc[m][n][r];
            }
        }
    }
}

// ---------------------------------------------------------------------------
// Kernel 3: out = (P0+P1+P2+P3) + bias
// ---------------------------------------------------------------------------
__global__ __launch_bounds__(256) void k_reduce(const float* __restrict__ P,
                                                const f32x4* __restrict__ bias4,
                                                f32x4* __restrict__ out4) {
    const int idx = blockIdx.x * 256 + threadIdx.x;     // (i,col) flat, 1M total
    const size_t STR = (size_t)NN * FOUT;
    float s = (P[idx] + P[idx + STR]) + (P[idx + 2 * STR] + P[idx + 3 * STR]);
    f32x4 bv = bias4[idx];
    f32x4 o;
    o.x = s + bv.x; o.y = s + bv.y; o.z = s + bv.z; o.w = s + bv.w;
    out4[idx] = o;
}

// ---------------------------------------------------------------------------
extern "C" void kernel_launch(void* const* d_in, const int* in_sizes, int n_in,
                              void* d_out, int out_size, void* d_ws, size_t ws_size,
                              hipStream_t stream) {
    const float* x     = (const float*)d_in[0];    // [4096][512] f32
    const f32x4* adjs4 = (const f32x4*)d_in[1];    // [4096][4096] x f32x4 (C=4)
    const f32x4* w4    = (const f32x4*)d_in[2];    // [512][256] x f32x4
    const f32x4* bias4 = (const f32x4*)d_in[3];    // [4096][256] x f32x4
    f32x4*       out4  = (f32x4*)d_out;            // [4096][256] x f32x4

    char* ws = (char*)d_ws;
    unsigned short* wsumT = (unsigned short*)ws;                       // 256 KiB
    unsigned short* Ht    = (unsigned short*)(ws + 262144);            // 2 MiB
    float*          Pp    = (float*)(ws + 262144 + 2097152);           // 16 MiB

    k_prep_wsum<<<(FIN * FOUT) / 256, 256, 0, stream>>>(w4, wsumT);
    k_gemm_h<<<NN / 16, 512, 0, stream>>>(x, wsumT, Ht);
    k_gemm_big<<<256, 512, 0, stream>>>(adjs4, Ht, Pp);
    k_reduce<<<(NN * FOUT) / 256, 256, 0, stream>>>(Pp, bias4, out4);
}